// Round 2
// baseline (24273.555 us; speedup 1.0000x reference)
//
#include <hip/hip_runtime.h>
#include <hip/hip_bf16.h>

typedef float f32x4 __attribute__((ext_vector_type(4)));
typedef short bf16x8 __attribute__((ext_vector_type(8)));

#define MFMA16x32(a,b,c) __builtin_amdgcn_mfma_f32_16x16x32_bf16((a),(b),(c),0,0,0)

__device__ __forceinline__ unsigned short f2bf(float f) {
  unsigned u = __float_as_uint(f);
  u += 0x7fffu + ((u >> 16) & 1u);
  return (unsigned short)(u >> 16);
}

// ---------------- workspace layout (bytes) ----------------
#define WS_G1BLOB 0ull
#define WS_G3BLOB 8388608ull
#define WS_WOUTT  25165824ull
#define WS_H1BUF  33554432ull
#define WS_H2BUF  33816576ull
#define WS_BAR    34078720ull
#define WS_H2ALL  34078976ull

// ---------------- init: zero H buffers + barrier ----------------
__global__ void k_init(unsigned* __restrict__ p, int n) {
  int i = blockIdx.x * blockDim.x + threadIdx.x;
  for (; i < n; i += gridDim.x * blockDim.x) p[i] = 0u;
}

// ---------------- pack W1h into per-wave B-fragment blob ----------------
__global__ void k_pack_g1(const float* __restrict__ W1, unsigned short* __restrict__ blob) {
  int gtid = blockIdx.x * 256 + threadIdx.x;      // 524288 threads
  int lane = gtid & 63, kk = (gtid >> 6) & 31, w = gtid >> 11;
  int c = lane & 15, q = lane >> 4;
  int g = c >> 2, h = w * 4 + (c & 3);
  bf16x8 s;
#pragma unroll
  for (int j = 0; j < 8; ++j) {
    int k = kk * 32 + q * 8 + j;
    float v = W1[(size_t)g * 5242880u + (size_t)(4096 + k) * 1024u + h];
    ((unsigned short*)&s)[j] = f2bf(v);
  }
  ((bf16x8*)blob)[(size_t)(w * 32 + kk) * 64 + lane] = s;
}

// ---------------- pack W2 (kk<32 -> W2h rows 1024+, kk>=32 -> W2x rows 0..1023) ----------------
__global__ void k_pack_g3(const float* __restrict__ W2, unsigned short* __restrict__ blob) {
  int gtid = blockIdx.x * 256 + threadIdx.x;      // 1048576 threads
  int lane = gtid & 63, kk = (gtid >> 6) & 63, w = gtid >> 12;
  int c = lane & 15, q = lane >> 4;
  int g = c >> 2, h = w * 4 + (c & 3);
  bf16x8 s;
#pragma unroll
  for (int j = 0; j < 8; ++j) {
    int klocal = (kk & 31) * 32 + q * 8 + j;
    int d = (kk < 32) ? (1024 + klocal) : klocal;
    float v = W2[(size_t)g * 2097152u + (size_t)d * 1024u + h];
    ((unsigned short*)&s)[j] = f2bf(v);
  }
  ((bf16x8*)blob)[(size_t)(w * 64 + kk) * 64 + lane] = s;
}

// ---------------- Wout^T bf16 ----------------
__global__ void k_pack_woutT(const float* __restrict__ Wout, unsigned short* __restrict__ wT) {
  int gtid = blockIdx.x * 256 + threadIdx.x;      // 4,194,304 threads
  int k = gtid & 1023, n = gtid >> 10;
  wT[(size_t)n * 1024 + k] = f2bf(Wout[(size_t)k * 4096 + n]);
}

// ---------------- device-scope grid barrier (monotonic epoch, poison-guarded) ----------------
__device__ __forceinline__ void gbar(unsigned* barv, unsigned epoch) {
  __syncthreads();
  if (threadIdx.x == 0) {
    if (__hip_atomic_load(&barv[48], __ATOMIC_RELAXED, __HIP_MEMORY_SCOPE_AGENT) == 0u) {
      __threadfence();
      unsigned prev = __hip_atomic_fetch_add(&barv[0], 1u, __ATOMIC_ACQ_REL, __HIP_MEMORY_SCOPE_AGENT);
      if (prev == epoch * 128u - 1u) {
        __hip_atomic_store(&barv[32], epoch, __ATOMIC_RELEASE, __HIP_MEMORY_SCOPE_AGENT);
      } else {
        unsigned guard = 0;
        while (__hip_atomic_load(&barv[32], __ATOMIC_ACQUIRE, __HIP_MEMORY_SCOPE_AGENT) < epoch) {
          __builtin_amdgcn_s_sleep(2);
          if (++guard > (1u << 24)) {  // fail-visible, never hard-hang
            __hip_atomic_store(&barv[48], 1u, __ATOMIC_RELAXED, __HIP_MEMORY_SCOPE_AGENT);
            break;
          }
        }
      }
    }
  }
  __syncthreads();
}

// ---------------- persistent recurrent kernel (REGULAR launch, 128 blocks) ----------------
// blocks 0..63  (G1): g1 = gather + H1@W1h + b1 -> ew -> H1n, C1 (in regs)
// blocks 64..127(G3): phaseA: acc = b2 + H2@W2h ; phaseC: acc += H1n@W2x -> ew -> H2n, C2
__global__ __launch_bounds__(256, 1) void k_lstm(
    const int* __restrict__ tokens, const float* __restrict__ W1,
    const float* __restrict__ b1, const float* __restrict__ b2,
    const unsigned short* __restrict__ g1blob, const unsigned short* __restrict__ g3blob,
    unsigned short* __restrict__ h1buf, unsigned short* __restrict__ h2buf,
    unsigned short* __restrict__ h2all, float* __restrict__ outF,
    unsigned* __restrict__ barv)
{
  const int tid = threadIdx.x, lane = tid & 63, widx = tid >> 6, bid = blockIdx.x;
  const int c = lane & 15, q = lane >> 4;
  const bool isG1 = bid < 64;
  const int w = (isG1 ? bid : bid - 64) * 4 + widx;   // 0..255 within role
  const int g = c >> 2;
  const int hcol = w * 4 + (c & 3);                   // this lane's weight column h
  const int h_ew = w * 4 + (lane & 3);                // elementwise target h

  // --- preload weight fragments into registers ---
  bf16x8 Breg[64];
  {
    const bf16x8* blob1 = (const bf16x8*)g1blob;
    const bf16x8* blob3 = (const bf16x8*)g3blob;
#pragma unroll
    for (int kk = 0; kk < 32; ++kk)
      Breg[kk] = isG1 ? blob1[(size_t)(w * 32 + kk) * 64 + lane]
                      : blob3[(size_t)(w * 64 + kk) * 64 + lane];
    if (!isG1) {
#pragma unroll
      for (int kk = 32; kk < 64; ++kk)
        Breg[kk] = blob3[(size_t)(w * 64 + kk) * 64 + lane];
    }
  }
  const float biasv = isG1 ? b1[g * 1024 + hcol] : b2[g * 1024 + hcol];

  float Cst[16];
#pragma unroll
  for (int i = 0; i < 16; ++i) Cst[i] = 0.f;

  // --- G1: preload embedding gathers for t=0 ---
  float gv[16];
  if (isG1) {
#pragma unroll
    for (int m = 0; m < 4; ++m)
#pragma unroll
      for (int r = 0; r < 4; ++r) {
        int b_ = m * 16 + q * 4 + r;
        int tk = tokens[b_ * 256];
        gv[m * 4 + r] = W1[(size_t)g * 5242880u + (size_t)tk * 1024u + hcol];
      }
  }

  unsigned epoch = 0;
  f32x4 acc[4];

#pragma clang loop unroll(disable)
  for (int t = 0; t < 256; ++t) {
    const int rp = t & 1, wpar = rp ^ 1;

    if (isG1) {
      int tk2[16];
      const int tn = (t < 255) ? t + 1 : 255;
#pragma unroll
      for (int m = 0; m < 4; ++m)
#pragma unroll
        for (int r = 0; r < 4; ++r)
          tk2[m * 4 + r] = tokens[(m * 16 + q * 4 + r) * 256 + tn];

#pragma unroll
      for (int m = 0; m < 4; ++m) acc[m] = (f32x4){0.f, 0.f, 0.f, 0.f};
      const unsigned short* Hrd = h1buf + rp * 65536;
#pragma unroll
      for (int kk = 0; kk < 32; ++kk) {
#pragma unroll
        for (int m = 0; m < 4; ++m) {
          bf16x8 a = *(const bf16x8*)(Hrd + (m * 16 + c) * 1024 + kk * 32 + q * 8);
          acc[m] = MFMA16x32(a, Breg[kk], acc[m]);
        }
      }
      // elementwise LSTM (gates in cols: f,i,o,ct at lanes sb|{0,4,8,12})
#pragma unroll
      for (int m = 0; m < 4; ++m) {
#pragma unroll
        for (int r = 0; r < 4; ++r) {
          float v = acc[m][r] + gv[m * 4 + r] + biasv;
          const int sb = (lane & 48) | (lane & 3);
          float vf = __shfl(v, sb, 64);
          float vi = __shfl(v, sb | 4, 64);
          float vo = __shfl(v, sb | 8, 64);
          float vc = __shfl(v, sb | 12, 64);
          float fg = 1.f / (1.f + __expf(-vf));
          float ig = 1.f / (1.f + __expf(-vi));
          float og = 1.f / (1.f + __expf(-vo));
          float e2 = __expf(2.f * vc);
          float ct = (e2 - 1.f) / (e2 + 1.f);
          float Cn = fg * Cst[m * 4 + r] + ig * ct;
          Cst[m * 4 + r] = Cn;
          float e2c = __expf(2.f * Cn);
          float Hn = og * (e2c - 1.f) / (e2c + 1.f);
          if ((lane & 12) == 0) {
            int row = m * 16 + q * 4 + r;
            h1buf[wpar * 65536 + row * 1024 + h_ew] = f2bf(Hn);
            if (t == 255) {
              outF[row * 1024 + h_ew] = Hn;           // H1 final
              outF[65536 + row * 1024 + h_ew] = Cn;   // C1 final
            }
          }
        }
      }
      // prefetch next step's embedding gathers
#pragma unroll
      for (int i = 0; i < 16; ++i)
        gv[i] = W1[(size_t)g * 5242880u + (size_t)tk2[i] * 1024u + hcol];
    } else {
      // G3 phase A: acc = b2 + H2(t-1) @ W2h
#pragma unroll
      for (int m = 0; m < 4; ++m) acc[m] = (f32x4){biasv, biasv, biasv, biasv};
      const unsigned short* Hrd = h2buf + rp * 65536;
#pragma unroll
      for (int kk = 0; kk < 32; ++kk) {
#pragma unroll
        for (int m = 0; m < 4; ++m) {
          bf16x8 a = *(const bf16x8*)(Hrd + (m * 16 + c) * 1024 + kk * 32 + q * 8);
          acc[m] = MFMA16x32(a, Breg[kk], acc[m]);
        }
      }
    }

    ++epoch; gbar(barv, epoch);   // H1n published

    if (!isG1) {
      // G3 phase C: acc += H1n @ W2x, then elementwise
      const unsigned short* Hrd = h1buf + wpar * 65536;
#pragma unroll
      for (int kk = 32; kk < 64; ++kk) {
#pragma unroll
        for (int m = 0; m < 4; ++m) {
          bf16x8 a = *(const bf16x8*)(Hrd + (m * 16 + c) * 1024 + (kk - 32) * 32 + q * 8);
          acc[m] = MFMA16x32(a, Breg[kk], acc[m]);
        }
      }
#pragma unroll
      for (int m = 0; m < 4; ++m) {
#pragma unroll
        for (int r = 0; r < 4; ++r) {
          float v = acc[m][r];
          const int sb = (lane & 48) | (lane & 3);
          float vf = __shfl(v, sb, 64);
          float vi = __shfl(v, sb | 4, 64);
          float vo = __shfl(v, sb | 8, 64);
          float vc = __shfl(v, sb | 12, 64);
          float fg = 1.f / (1.f + __expf(-vf));
          float ig = 1.f / (1.f + __expf(-vi));
          float og = 1.f / (1.f + __expf(-vo));
          float e2 = __expf(2.f * vc);
          float ct = (e2 - 1.f) / (e2 + 1.f);
          float Cn = fg * Cst[m * 4 + r] + ig * ct;
          Cst[m * 4 + r] = Cn;
          float e2c = __expf(2.f * Cn);
          float Hn = og * (e2c - 1.f) / (e2c + 1.f);
          if ((lane & 12) == 0) {
            int row = m * 16 + q * 4 + r;
            unsigned short hb = f2bf(Hn);
            h2buf[wpar * 65536 + row * 1024 + h_ew] = hb;
            h2all[((size_t)t * 64 + row) * 1024 + h_ew] = hb;
            if (t == 255) {
              outF[131072 + row * 1024 + h_ew] = Hn;  // H2 final
              outF[196608 + row * 1024 + h_ew] = Cn;  // C2 final
            }
          }
        }
      }
    }

    ++epoch; gbar(barv, epoch);   // H2n published
  }
}

// ---------------- output projection: Y = H2all @ Wout + bout ----------------
__global__ __launch_bounds__(256, 2) void k_gemm_out(
    const unsigned short* __restrict__ A, const unsigned short* __restrict__ Bt,
    const float* __restrict__ bout, float* __restrict__ C)
{
  __shared__ unsigned short As[128 * 32];
  __shared__ unsigned short Bs[128 * 32];
  const int tid = threadIdx.x, lane = tid & 63, wv = tid >> 6;
  const int c = lane & 15, q = lane >> 4;
  const int bn = blockIdx.x & 31, bm = blockIdx.x >> 5;
  const int wm = wv >> 1, wn = wv & 1;

  f32x4 acc[4][4];
#pragma unroll
  for (int m = 0; m < 4; ++m)
#pragma unroll
    for (int n = 0; n < 4; ++n) acc[m][n] = (f32x4){0.f, 0.f, 0.f, 0.f};

  const unsigned short* Abase = A + (size_t)(bm * 128) * 1024;
  const unsigned short* Bbase = Bt + (size_t)(bn * 128) * 1024;

  for (int kt = 0; kt < 32; ++kt) {
    if (kt) __syncthreads();
#pragma unroll
    for (int ch = 0; ch < 2; ++ch) {
      int o = ch * 4096 + tid * 16;          // byte offset within 8KB tile
      int row = o >> 6;
      int ks = (o & 63) >> 1;
      *(bf16x8*)&As[o >> 1] = *(const bf16x8*)(Abase + (size_t)row * 1024 + kt * 32 + ks);
      *(bf16x8*)&Bs[o >> 1] = *(const bf16x8*)(Bbase + (size_t)row * 1024 + kt * 32 + ks);
    }
    __syncthreads();
    bf16x8 af[4], bfr[4];
#pragma unroll
    for (int m = 0; m < 4; ++m) af[m] = *(const bf16x8*)&As[(wm * 64 + m * 16 + c) * 32 + q * 8];
#pragma unroll
    for (int n = 0; n < 4; ++n) bfr[n] = *(const bf16x8*)&Bs[(wn * 64 + n * 16 + c) * 32 + q * 8];
#pragma unroll
    for (int m = 0; m < 4; ++m)
#pragma unroll
      for (int n = 0; n < 4; ++n) acc[m][n] = MFMA16x32(af[m], bfr[n], acc[m][n]);
  }

#pragma unroll
  for (int n = 0; n < 4; ++n) {
    int col = bn * 128 + wn * 64 + n * 16 + c;
    float bo = bout[col];
#pragma unroll
    for (int m = 0; m < 4; ++m) {
      int row0 = bm * 128 + wm * 64 + m * 16 + q * 4;
#pragma unroll
      for (int r = 0; r < 4; ++r)
        C[(size_t)(row0 + r) * 4096 + col] = acc[m][n][r] + bo;
    }
  }
}

extern "C" void kernel_launch(void* const* d_in, const int* in_sizes, int n_in,
                              void* d_out, int out_size, void* d_ws, size_t ws_size,
                              hipStream_t stream) {
  const int* tokens = (const int*)d_in[0];
  const float* W1 = (const float*)d_in[1];
  const float* b1 = (const float*)d_in[2];
  const float* W2 = (const float*)d_in[3];
  const float* b2 = (const float*)d_in[4];
  const float* Wout = (const float*)d_in[5];
  const float* bout = (const float*)d_in[6];

  char* ws = (char*)d_ws;
  unsigned short* g1blob = (unsigned short*)(ws + WS_G1BLOB);
  unsigned short* g3blob = (unsigned short*)(ws + WS_G3BLOB);
  unsigned short* woutT  = (unsigned short*)(ws + WS_WOUTT);
  unsigned short* h1buf  = (unsigned short*)(ws + WS_H1BUF);
  unsigned short* h2buf  = (unsigned short*)(ws + WS_H2BUF);
  unsigned*       barv   = (unsigned*)(ws + WS_BAR);
  unsigned short* h2all  = (unsigned short*)(ws + WS_H2ALL);

  float* outY = (float*)d_out;
  float* outF = outY + 67108864;   // Y then H1,C1,H2,C2

  hipLaunchKernelGGL(k_init, dim3(128), dim3(256), 0, stream,
                     (unsigned*)(ws + WS_H1BUF), 131136);
  hipLaunchKernelGGL(k_pack_g1, dim3(2048), dim3(256), 0, stream, W1, g1blob);
  hipLaunchKernelGGL(k_pack_g3, dim3(4096), dim3(256), 0, stream, W2, g3blob);
  hipLaunchKernelGGL(k_pack_woutT, dim3(16384), dim3(256), 0, stream, Wout, woutT);

  // regular launch: 128 blocks x 256 thr trivially co-resident on 256 CUs
  hipLaunchKernelGGL(k_lstm, dim3(128), dim3(256), 0, stream,
                     tokens, W1, b1, b2, g1blob, g3blob, h1buf, h2buf,
                     h2all, outF, barv);

  hipLaunchKernelGGL(k_gemm_out, dim3(4096), dim3(256), 0, stream, h2all, woutT, bout, outY);
}

// Round 4
// 16883.182 us; speedup vs baseline: 1.4377x; 1.4377x over previous
//
#include <hip/hip_runtime.h>
#include <hip/hip_bf16.h>

typedef float f32x4 __attribute__((ext_vector_type(4)));
typedef short bf16x8 __attribute__((ext_vector_type(8)));

#define MFMA16x32(a,b,c) __builtin_amdgcn_mfma_f32_16x16x32_bf16((a),(b),(c),0,0,0)

__device__ __forceinline__ unsigned short f2bf(float f) {
  unsigned u = __float_as_uint(f);
  u += 0x7fffu + ((u >> 16) & 1u);
  return (unsigned short)(u >> 16);
}

// ---------------- workspace layout (bytes) ----------------
#define WS_G1BLOB 0ull
#define WS_G3BLOB 8388608ull
#define WS_WOUTT  25165824ull
#define WS_H1BUF  33554432ull
#define WS_H2BUF  33816576ull
#define WS_BAR    34078720ull
#define WS_H2ALL  34078976ull

// ---------------- init: zero H buffers + barrier ----------------
__global__ void k_init(unsigned* __restrict__ p, int n) {
  int i = blockIdx.x * blockDim.x + threadIdx.x;
  for (; i < n; i += gridDim.x * blockDim.x) p[i] = 0u;
}

// ---------------- pack W1h into per-wave B-fragment blob ----------------
__global__ void k_pack_g1(const float* __restrict__ W1, unsigned short* __restrict__ blob) {
  int gtid = blockIdx.x * 256 + threadIdx.x;      // 524288 threads
  int lane = gtid & 63, kk = (gtid >> 6) & 31, w = gtid >> 11;
  int c = lane & 15, q = lane >> 4;
  int g = c >> 2, h = w * 4 + (c & 3);
  bf16x8 s;
#pragma unroll
  for (int j = 0; j < 8; ++j) {
    int k = kk * 32 + q * 8 + j;
    float v = W1[(size_t)g * 5242880u + (size_t)(4096 + k) * 1024u + h];
    ((unsigned short*)&s)[j] = f2bf(v);
  }
  ((bf16x8*)blob)[(size_t)(w * 32 + kk) * 64 + lane] = s;
}

// ---------------- pack W2 (kk<32 -> W2h rows 1024+, kk>=32 -> W2x rows 0..1023) ----------------
__global__ void k_pack_g3(const float* __restrict__ W2, unsigned short* __restrict__ blob) {
  int gtid = blockIdx.x * 256 + threadIdx.x;      // 1048576 threads
  int lane = gtid & 63, kk = (gtid >> 6) & 63, w = gtid >> 12;
  int c = lane & 15, q = lane >> 4;
  int g = c >> 2, h = w * 4 + (c & 3);
  bf16x8 s;
#pragma unroll
  for (int j = 0; j < 8; ++j) {
    int klocal = (kk & 31) * 32 + q * 8 + j;
    int d = (kk < 32) ? (1024 + klocal) : klocal;
    float v = W2[(size_t)g * 2097152u + (size_t)d * 1024u + h];
    ((unsigned short*)&s)[j] = f2bf(v);
  }
  ((bf16x8*)blob)[(size_t)(w * 64 + kk) * 64 + lane] = s;
}

// ---------------- Wout^T bf16 ----------------
__global__ void k_pack_woutT(const float* __restrict__ Wout, unsigned short* __restrict__ wT) {
  int gtid = blockIdx.x * 256 + threadIdx.x;      // 4,194,304 threads
  int k = gtid & 1023, n = gtid >> 10;
  wT[(size_t)n * 1024 + k] = f2bf(Wout[(size_t)k * 4096 + n]);
}

// ---------------- device-scope grid barrier ----------------
// Arrive: fetch_add ACQ_REL (releases this block's H-writes; last block acquires all).
// Last block: flag store RELEASE. Waiters: RELAXED spin (no per-poll invalidate!)
// + ONE agent-scope ACQUIRE fence after the flag flips.
__device__ __forceinline__ void gbar(unsigned* barv, unsigned epoch) {
  __syncthreads();
  if (threadIdx.x == 0) {
    if (__hip_atomic_load(&barv[48], __ATOMIC_RELAXED, __HIP_MEMORY_SCOPE_AGENT) == 0u) {
      unsigned prev = __hip_atomic_fetch_add(&barv[0], 1u, __ATOMIC_ACQ_REL, __HIP_MEMORY_SCOPE_AGENT);
      if (prev == epoch * 128u - 1u) {
        __hip_atomic_store(&barv[32], epoch, __ATOMIC_RELEASE, __HIP_MEMORY_SCOPE_AGENT);
      } else {
        unsigned guard = 0;
        while (__hip_atomic_load(&barv[32], __ATOMIC_RELAXED, __HIP_MEMORY_SCOPE_AGENT) < epoch) {
          __builtin_amdgcn_s_sleep(8);
          if (++guard > (1u << 20)) {  // fail-visible, never hard-hang
            __hip_atomic_store(&barv[48], 1u, __ATOMIC_RELAXED, __HIP_MEMORY_SCOPE_AGENT);
            break;
          }
        }
        __builtin_amdgcn_fence(__ATOMIC_ACQUIRE, "agent");
      }
    }
  }
  __syncthreads();
}

// ---------------- persistent recurrent kernel (128 blocks) ----------------
// blocks 0..63  (G1): g1 = gather + H1@W1h + b1 -> ew -> H1n, C1 (in regs)
// blocks 64..127(G3): phaseA: acc = b2 + H2@W2h ; phaseC: acc += H1n@W2x -> ew -> H2n, C2
__global__ __launch_bounds__(256, 1) void k_lstm(
    const int* __restrict__ tokens, const float* __restrict__ W1,
    const float* __restrict__ b1, const float* __restrict__ b2,
    const unsigned short* __restrict__ g1blob, const unsigned short* __restrict__ g3blob,
    unsigned short* __restrict__ h1buf, unsigned short* __restrict__ h2buf,
    unsigned short* __restrict__ h2all, float* __restrict__ outF,
    unsigned* __restrict__ barv)
{
  const int tid = threadIdx.x, lane = tid & 63, widx = tid >> 6, bid = blockIdx.x;
  const int c = lane & 15, q = lane >> 4;
  const bool isG1 = bid < 64;
  const int w = (isG1 ? bid : bid - 64) * 4 + widx;   // 0..255 within role
  const int g = c >> 2;
  const int hcol = w * 4 + (c & 3);                   // this lane's weight column h
  const int h_ew = w * 4 + (lane & 3);                // elementwise target h

  // --- preload weight fragments into registers ---
  bf16x8 Breg[64];
  {
    const bf16x8* blob1 = (const bf16x8*)g1blob;
    const bf16x8* blob3 = (const bf16x8*)g3blob;
#pragma unroll
    for (int kk = 0; kk < 32; ++kk)
      Breg[kk] = isG1 ? blob1[(size_t)(w * 32 + kk) * 64 + lane]
                      : blob3[(size_t)(w * 64 + kk) * 64 + lane];
    if (!isG1) {
#pragma unroll
      for (int kk = 32; kk < 64; ++kk)
        Breg[kk] = blob3[(size_t)(w * 64 + kk) * 64 + lane];
    }
  }
  const float biasv = isG1 ? b1[g * 1024 + hcol] : b2[g * 1024 + hcol];

  float Cst[16];
#pragma unroll
  for (int i = 0; i < 16; ++i) Cst[i] = 0.f;

  // --- G1: preload embedding gathers for t=0 ---
  float gv[16];
  if (isG1) {
#pragma unroll
    for (int m = 0; m < 4; ++m)
#pragma unroll
      for (int r = 0; r < 4; ++r) {
        int b_ = m * 16 + q * 4 + r;
        int tk = tokens[b_ * 256];
        gv[m * 4 + r] = W1[(size_t)g * 5242880u + (size_t)tk * 1024u + hcol];
      }
  }

  unsigned epoch = 0;
  f32x4 acc[4];

#pragma clang loop unroll(disable)
  for (int t = 0; t < 256; ++t) {
    const int rp = t & 1, wpar = rp ^ 1;

    if (isG1) {
      int tk2[16];
      const int tn = (t < 255) ? t + 1 : 255;
#pragma unroll
      for (int m = 0; m < 4; ++m)
#pragma unroll
        for (int r = 0; r < 4; ++r)
          tk2[m * 4 + r] = tokens[(m * 16 + q * 4 + r) * 256 + tn];

#pragma unroll
      for (int m = 0; m < 4; ++m) acc[m] = (f32x4){0.f, 0.f, 0.f, 0.f};
      const unsigned short* Hrd = h1buf + rp * 65536;
#pragma unroll
      for (int kk = 0; kk < 32; ++kk) {
#pragma unroll
        for (int m = 0; m < 4; ++m) {
          bf16x8 a = *(const bf16x8*)(Hrd + (m * 16 + c) * 1024 + kk * 32 + q * 8);
          acc[m] = MFMA16x32(a, Breg[kk], acc[m]);
        }
      }
      // elementwise LSTM (gates in cols: f,i,o,ct at lanes sb|{0,4,8,12})
#pragma unroll
      for (int m = 0; m < 4; ++m) {
#pragma unroll
        for (int r = 0; r < 4; ++r) {
          float v = acc[m][r] + gv[m * 4 + r] + biasv;
          const int sb = (lane & 48) | (lane & 3);
          float vf = __shfl(v, sb, 64);
          float vi = __shfl(v, sb | 4, 64);
          float vo = __shfl(v, sb | 8, 64);
          float vc = __shfl(v, sb | 12, 64);
          float fg = 1.f / (1.f + __expf(-vf));
          float ig = 1.f / (1.f + __expf(-vi));
          float og = 1.f / (1.f + __expf(-vo));
          float e2 = __expf(2.f * vc);
          float ct = (e2 - 1.f) / (e2 + 1.f);
          float Cn = fg * Cst[m * 4 + r] + ig * ct;
          Cst[m * 4 + r] = Cn;
          float e2c = __expf(2.f * Cn);
          float Hn = og * (e2c - 1.f) / (e2c + 1.f);
          if ((lane & 12) == 0) {
            int row = m * 16 + q * 4 + r;
            h1buf[wpar * 65536 + row * 1024 + h_ew] = f2bf(Hn);
            if (t == 255) {
              outF[row * 1024 + h_ew] = Hn;           // H1 final
              outF[65536 + row * 1024 + h_ew] = Cn;   // C1 final
            }
          }
        }
      }
      // prefetch next step's embedding gathers
#pragma unroll
      for (int i = 0; i < 16; ++i)
        gv[i] = W1[(size_t)g * 5242880u + (size_t)tk2[i] * 1024u + hcol];
    } else {
      // G3 phase A: acc = b2 + H2(t-1) @ W2h
#pragma unroll
      for (int m = 0; m < 4; ++m) acc[m] = (f32x4){biasv, biasv, biasv, biasv};
      const unsigned short* Hrd = h2buf + rp * 65536;
#pragma unroll
      for (int kk = 0; kk < 32; ++kk) {
#pragma unroll
        for (int m = 0; m < 4; ++m) {
          bf16x8 a = *(const bf16x8*)(Hrd + (m * 16 + c) * 1024 + kk * 32 + q * 8);
          acc[m] = MFMA16x32(a, Breg[kk], acc[m]);
        }
      }
    }

    ++epoch; gbar(barv, epoch);   // H1n published

    if (!isG1) {
      // G3 phase C: acc += H1n @ W2x, then elementwise
      const unsigned short* Hrd = h1buf + wpar * 65536;
#pragma unroll
      for (int kk = 32; kk < 64; ++kk) {
#pragma unroll
        for (int m = 0; m < 4; ++m) {
          bf16x8 a = *(const bf16x8*)(Hrd + (m * 16 + c) * 1024 + (kk - 32) * 32 + q * 8);
          acc[m] = MFMA16x32(a, Breg[kk], acc[m]);
        }
      }
#pragma unroll
      for (int m = 0; m < 4; ++m) {
#pragma unroll
        for (int r = 0; r < 4; ++r) {
          float v = acc[m][r];
          const int sb = (lane & 48) | (lane & 3);
          float vf = __shfl(v, sb, 64);
          float vi = __shfl(v, sb | 4, 64);
          float vo = __shfl(v, sb | 8, 64);
          float vc = __shfl(v, sb | 12, 64);
          float fg = 1.f / (1.f + __expf(-vf));
          float ig = 1.f / (1.f + __expf(-vi));
          float og = 1.f / (1.f + __expf(-vo));
          float e2 = __expf(2.f * vc);
          float ct = (e2 - 1.f) / (e2 + 1.f);
          float Cn = fg * Cst[m * 4 + r] + ig * ct;
          Cst[m * 4 + r] = Cn;
          float e2c = __expf(2.f * Cn);
          float Hn = og * (e2c - 1.f) / (e2c + 1.f);
          if ((lane & 12) == 0) {
            int row = m * 16 + q * 4 + r;
            unsigned short hb = f2bf(Hn);
            h2buf[wpar * 65536 + row * 1024 + h_ew] = hb;
            h2all[((size_t)t * 64 + row) * 1024 + h_ew] = hb;
            if (t == 255) {
              outF[131072 + row * 1024 + h_ew] = Hn;  // H2 final
              outF[196608 + row * 1024 + h_ew] = Cn;  // C2 final
            }
          }
        }
      }
    }

    ++epoch; gbar(barv, epoch);   // H2n published
  }
}

// ---------------- output projection: Y = H2all @ Wout + bout ----------------
__global__ __launch_bounds__(256, 2) void k_gemm_out(
    const unsigned short* __restrict__ A, const unsigned short* __restrict__ Bt,
    const float* __restrict__ bout, float* __restrict__ C)
{
  __shared__ unsigned short As[128 * 32];
  __shared__ unsigned short Bs[128 * 32];
  const int tid = threadIdx.x, lane = tid & 63, wv = tid >> 6;
  const int c = lane & 15, q = lane >> 4;
  const int bn = blockIdx.x & 31, bm = blockIdx.x >> 5;
  const int wm = wv >> 1, wn = wv & 1;

  f32x4 acc[4][4];
#pragma unroll
  for (int m = 0; m < 4; ++m)
#pragma unroll
    for (int n = 0; n < 4; ++n) acc[m][n] = (f32x4){0.f, 0.f, 0.f, 0.f};

  const unsigned short* Abase = A + (size_t)(bm * 128) * 1024;
  const unsigned short* Bbase = Bt + (size_t)(bn * 128) * 1024;

  for (int kt = 0; kt < 32; ++kt) {
    if (kt) __syncthreads();
#pragma unroll
    for (int ch = 0; ch < 2; ++ch) {
      int o = ch * 4096 + tid * 16;          // byte offset within 8KB tile
      int row = o >> 6;
      int ks = (o & 63) >> 1;
      *(bf16x8*)&As[o >> 1] = *(const bf16x8*)(Abase + (size_t)row * 1024 + kt * 32 + ks);
      *(bf16x8*)&Bs[o >> 1] = *(const bf16x8*)(Bbase + (size_t)row * 1024 + kt * 32 + ks);
    }
    __syncthreads();
    bf16x8 af[4], bfr[4];
#pragma unroll
    for (int m = 0; m < 4; ++m) af[m] = *(const bf16x8*)&As[(wm * 64 + m * 16 + c) * 32 + q * 8];
#pragma unroll
    for (int n = 0; n < 4; ++n) bfr[n] = *(const bf16x8*)&Bs[(wn * 64 + n * 16 + c) * 32 + q * 8];
#pragma unroll
    for (int m = 0; m < 4; ++m)
#pragma unroll
      for (int n = 0; n < 4; ++n) acc[m][n] = MFMA16x32(af[m], bfr[n], acc[m][n]);
  }

#pragma unroll
  for (int n = 0; n < 4; ++n) {
    int col = bn * 128 + wn * 64 + n * 16 + c;
    float bo = bout[col];
#pragma unroll
    for (int m = 0; m < 4; ++m) {
      int row0 = bm * 128 + wm * 64 + m * 16 + q * 4;
#pragma unroll
      for (int r = 0; r < 4; ++r)
        C[(size_t)(row0 + r) * 4096 + col] = acc[m][n][r] + bo;
    }
  }
}

extern "C" void kernel_launch(void* const* d_in, const int* in_sizes, int n_in,
                              void* d_out, int out_size, void* d_ws, size_t ws_size,
                              hipStream_t stream) {
  const int* tokens = (const int*)d_in[0];
  const float* W1 = (const float*)d_in[1];
  const float* b1 = (const float*)d_in[2];
  const float* W2 = (const float*)d_in[3];
  const float* b2 = (const float*)d_in[4];
  const float* Wout = (const float*)d_in[5];
  const float* bout = (const float*)d_in[6];

  char* ws = (char*)d_ws;
  unsigned short* g1blob = (unsigned short*)(ws + WS_G1BLOB);
  unsigned short* g3blob = (unsigned short*)(ws + WS_G3BLOB);
  unsigned short* woutT  = (unsigned short*)(ws + WS_WOUTT);
  unsigned short* h1buf  = (unsigned short*)(ws + WS_H1BUF);
  unsigned short* h2buf  = (unsigned short*)(ws + WS_H2BUF);
  unsigned*       barv   = (unsigned*)(ws + WS_BAR);
  unsigned short* h2all  = (unsigned short*)(ws + WS_H2ALL);

  float* outY = (float*)d_out;
  float* outF = outY + 67108864;   // Y then H1,C1,H2,C2

  hipLaunchKernelGGL(k_init, dim3(128), dim3(256), 0, stream,
                     (unsigned*)(ws + WS_H1BUF), 131136);
  hipLaunchKernelGGL(k_pack_g1, dim3(2048), dim3(256), 0, stream, W1, g1blob);
  hipLaunchKernelGGL(k_pack_g3, dim3(4096), dim3(256), 0, stream, W2, g3blob);
  hipLaunchKernelGGL(k_pack_woutT, dim3(16384), dim3(256), 0, stream, Wout, woutT);

  hipLaunchKernelGGL(k_lstm, dim3(128), dim3(256), 0, stream,
                     tokens, W1, b1, b2, g1blob, g3blob, h1buf, h2buf,
                     h2all, outF, barv);

  hipLaunchKernelGGL(k_gemm_out, dim3(4096), dim3(256), 0, stream, h2all, woutT, bout, outY);
}

// Round 5
// 13059.082 us; speedup vs baseline: 1.8587x; 1.2928x over previous
//
#include <hip/hip_runtime.h>
#include <hip/hip_bf16.h>

typedef float f32x4 __attribute__((ext_vector_type(4)));
typedef short bf16x8 __attribute__((ext_vector_type(8)));

#define MFMA16x32(a,b,c) __builtin_amdgcn_mfma_f32_16x16x32_bf16((a),(b),(c),0,0,0)

__device__ __forceinline__ unsigned short f2bf(float f) {
  unsigned u = __float_as_uint(f);
  u += 0x7fffu + ((u >> 16) & 1u);
  return (unsigned short)(u >> 16);
}

// ---------------- workspace layout (bytes) ----------------
// g1blob 8MB | g3blob 16MB | woutT 8MB | h1ring 4x128KB | sync 16KB | h2all 32MB
#define WS_G1BLOB 0ull
#define WS_G3BLOB 8388608ull
#define WS_WOUTT  25165824ull
#define WS_H1RING 33554432ull
#define WS_SYNC   34078720ull
#define WS_H2ALL  34095104ull

#define SLSTRIDE 16   // u32 per sync slot (one 64B line per block)

// ---------------- init: zero sync region ----------------
__global__ void k_init(unsigned* __restrict__ p, int n) {
  int i = blockIdx.x * blockDim.x + threadIdx.x;
  for (; i < n; i += gridDim.x * blockDim.x) p[i] = 0u;
}

// ---------------- pack W1h into per-wave B-fragment blob ----------------
__global__ void k_pack_g1(const float* __restrict__ W1, unsigned short* __restrict__ blob) {
  int gtid = blockIdx.x * 256 + threadIdx.x;      // 524288 threads
  int lane = gtid & 63, kk = (gtid >> 6) & 31, w = gtid >> 11;
  int c = lane & 15, q = lane >> 4;
  int g = c >> 2, h = w * 4 + (c & 3);
  bf16x8 s;
#pragma unroll
  for (int j = 0; j < 8; ++j) {
    int k = kk * 32 + q * 8 + j;
    float v = W1[(size_t)g * 5242880u + (size_t)(4096 + k) * 1024u + h];
    ((unsigned short*)&s)[j] = f2bf(v);
  }
  ((bf16x8*)blob)[(size_t)(w * 32 + kk) * 64 + lane] = s;
}

// ---------------- pack W2 (kk<32 -> W2h rows 1024+, kk>=32 -> W2x rows 0..1023) ----------------
__global__ void k_pack_g3(const float* __restrict__ W2, unsigned short* __restrict__ blob) {
  int gtid = blockIdx.x * 256 + threadIdx.x;      // 1048576 threads
  int lane = gtid & 63, kk = (gtid >> 6) & 63, w = gtid >> 12;
  int c = lane & 15, q = lane >> 4;
  int g = c >> 2, h = w * 4 + (c & 3);
  bf16x8 s;
#pragma unroll
  for (int j = 0; j < 8; ++j) {
    int klocal = (kk & 31) * 32 + q * 8 + j;
    int d = (kk < 32) ? (1024 + klocal) : klocal;
    float v = W2[(size_t)g * 2097152u + (size_t)d * 1024u + h];
    ((unsigned short*)&s)[j] = f2bf(v);
  }
  ((bf16x8*)blob)[(size_t)(w * 64 + kk) * 64 + lane] = s;
}

// ---------------- Wout^T bf16 ----------------
__global__ void k_pack_woutT(const float* __restrict__ Wout, unsigned short* __restrict__ wT) {
  int gtid = blockIdx.x * 256 + threadIdx.x;      // 4,194,304 threads
  int k = gtid & 1023, n = gtid >> 10;
  wT[(size_t)n * 1024 + k] = f2bf(Wout[(size_t)k * 4096 + n]);
}

// ---------------- flag-array sync primitives ----------------
// Wait until all 64 slots >= epoch. Wave 0: lane i polls slot i (own 64B line,
// RELAXED — no per-poll invalidate), then ONE agent acquire fence. Block-wide sync.
__device__ __forceinline__ void wait_slots(const unsigned* __restrict__ slots,
                                           unsigned epoch, unsigned* __restrict__ poison) {
  if (threadIdx.x < 64) {
    unsigned guard = 0;
    for (;;) {
      unsigned v = __hip_atomic_load(&slots[threadIdx.x * SLSTRIDE],
                                     __ATOMIC_RELAXED, __HIP_MEMORY_SCOPE_AGENT);
      if (__all((int)(v >= epoch))) break;
      __builtin_amdgcn_s_sleep(2);
      if (((++guard) & 1023u) == 0u) {
        if (guard > (1u << 18) ||
            __hip_atomic_load(poison, __ATOMIC_RELAXED, __HIP_MEMORY_SCOPE_AGENT) != 0u) {
          __hip_atomic_store(poison, 1u, __ATOMIC_RELAXED, __HIP_MEMORY_SCOPE_AGENT);
          break;   // fail-visible, never hard-hang
        }
      }
    }
    __builtin_amdgcn_fence(__ATOMIC_ACQUIRE, "agent");
  }
  __syncthreads();
}

// Publish: block-level HB via syncthreads, ONE agent release fence, relaxed store
// to this block's own slot line. No RMW — arrivals are contention-free.
__device__ __forceinline__ void publish_slot(unsigned* __restrict__ slots,
                                             int myslot, unsigned epoch) {
  __syncthreads();
  if (threadIdx.x == 0) {
    __builtin_amdgcn_fence(__ATOMIC_RELEASE, "agent");
    __hip_atomic_store(&slots[myslot * SLSTRIDE], epoch,
                       __ATOMIC_RELAXED, __HIP_MEMORY_SCOPE_AGENT);
  }
}

// ---------------- persistent recurrent kernel (128 blocks, two decoupled groups) ----------------
// G1 (blocks 0..63):  H1(t) = ew(gather + H1(t-1)@W1h + b1) -> h1ring[t&3]; barrier among G1 only.
// G3 (blocks 64..127): H2(t) = ew(b2 + H2(t-1)@W2h + H1(t)@W2x) -> h2all[t]; barrier among G3;
//                      waits on G1's slot array for H1(t); G1 backpressured to <=3 steps ahead.
__global__ __launch_bounds__(256, 1) void k_lstm(
    const int* __restrict__ tokens, const float* __restrict__ W1,
    const float* __restrict__ b1, const float* __restrict__ b2,
    const unsigned short* __restrict__ g1blob, const unsigned short* __restrict__ g3blob,
    unsigned short* __restrict__ h1ring, unsigned short* __restrict__ h2all,
    float* __restrict__ outF, unsigned* __restrict__ syncbase)
{
  const int tid = threadIdx.x, lane = tid & 63, widx = tid >> 6, bid = blockIdx.x;
  const int c = lane & 15, q = lane >> 4;
  const bool isG1 = bid < 64;
  const int myslot = isG1 ? bid : bid - 64;
  const int w = myslot * 4 + widx;                    // 0..255 within role
  const int g = c >> 2;
  const int hcol = w * 4 + (c & 3);
  const int h_ew = w * 4 + (lane & 3);

  unsigned* g1slots = syncbase;                       // 64 x 16 u32
  unsigned* g3slots = syncbase + 1024;
  unsigned* poison  = syncbase + 2048;

  // --- preload weight fragments into registers ---
  bf16x8 Breg[64];
  {
    const bf16x8* blob1 = (const bf16x8*)g1blob;
    const bf16x8* blob3 = (const bf16x8*)g3blob;
#pragma unroll
    for (int kk = 0; kk < 32; ++kk)
      Breg[kk] = isG1 ? blob1[(size_t)(w * 32 + kk) * 64 + lane]
                      : blob3[(size_t)(w * 64 + kk) * 64 + lane];
    if (!isG1) {
#pragma unroll
      for (int kk = 32; kk < 64; ++kk)
        Breg[kk] = blob3[(size_t)(w * 64 + kk) * 64 + lane];
    }
  }
  const float biasv = isG1 ? b1[g * 1024 + hcol] : b2[g * 1024 + hcol];

  float Cst[16];
#pragma unroll
  for (int i = 0; i < 16; ++i) Cst[i] = 0.f;

  // --- G1: preload embedding gathers for t=0 ---
  float gv[16];
  if (isG1) {
#pragma unroll
    for (int m = 0; m < 4; ++m)
#pragma unroll
      for (int r = 0; r < 4; ++r) {
        int b_ = m * 16 + q * 4 + r;
        int tk = tokens[b_ * 256];
        gv[m * 4 + r] = W1[(size_t)g * 5242880u + (size_t)tk * 1024u + hcol];
      }
  }

  f32x4 acc[4];

  if (isG1) {
    // ================= G1 chain =================
#pragma clang loop unroll(disable)
    for (int t = 0; t < 256; ++t) {
      if (t > 0) wait_slots(g1slots, (unsigned)t, poison);   // group barrier (all H1(t-1) visible)

      int tk2[16];
      const int tn = (t < 255) ? t + 1 : 255;
#pragma unroll
      for (int m = 0; m < 4; ++m)
#pragma unroll
        for (int r = 0; r < 4; ++r)
          tk2[m * 4 + r] = tokens[(m * 16 + q * 4 + r) * 256 + tn];

#pragma unroll
      for (int m = 0; m < 4; ++m) acc[m] = (f32x4){0.f, 0.f, 0.f, 0.f};
      if (t > 0) {
        const unsigned short* Hrd = h1ring + ((t - 1) & 3) * 65536;
#pragma unroll
        for (int kk = 0; kk < 32; ++kk) {
#pragma unroll
          for (int m = 0; m < 4; ++m) {
            bf16x8 a = *(const bf16x8*)(Hrd + (m * 16 + c) * 1024 + kk * 32 + q * 8);
            acc[m] = MFMA16x32(a, Breg[kk], acc[m]);
          }
        }
      }
      if (t >= 4) wait_slots(g3slots, (unsigned)(t - 3), poison);  // ring backpressure

#pragma unroll
      for (int m = 0; m < 4; ++m) {
#pragma unroll
        for (int r = 0; r < 4; ++r) {
          float v = acc[m][r] + gv[m * 4 + r] + biasv;
          const int sb = (lane & 48) | (lane & 3);
          float vf = __shfl(v, sb, 64);
          float vi = __shfl(v, sb | 4, 64);
          float vo = __shfl(v, sb | 8, 64);
          float vc = __shfl(v, sb | 12, 64);
          float fg = 1.f / (1.f + __expf(-vf));
          float ig = 1.f / (1.f + __expf(-vi));
          float og = 1.f / (1.f + __expf(-vo));
          float e2 = __expf(2.f * vc);
          float ct = (e2 - 1.f) / (e2 + 1.f);
          float Cn = fg * Cst[m * 4 + r] + ig * ct;
          Cst[m * 4 + r] = Cn;
          float e2c = __expf(2.f * Cn);
          float Hn = og * (e2c - 1.f) / (e2c + 1.f);
          if ((lane & 12) == 0) {
            int row = m * 16 + q * 4 + r;
            h1ring[(t & 3) * 65536 + row * 1024 + h_ew] = f2bf(Hn);
            if (t == 255) {
              outF[row * 1024 + h_ew] = Hn;           // H1 final
              outF[65536 + row * 1024 + h_ew] = Cn;   // C1 final
            }
          }
        }
      }
      publish_slot(g1slots, myslot, (unsigned)(t + 1));      // H1(t) published

      // prefetch next step's embedding gathers (overlaps barrier wait)
#pragma unroll
      for (int i = 0; i < 16; ++i)
        gv[i] = W1[(size_t)g * 5242880u + (size_t)tk2[i] * 1024u + hcol];
    }
  } else {
    // ================= G3 chain =================
#pragma clang loop unroll(disable)
    for (int t = 0; t < 256; ++t) {
      if (t > 0) wait_slots(g3slots, (unsigned)t, poison);   // group barrier (all H2(t-1) visible)

#pragma unroll
      for (int m = 0; m < 4; ++m) acc[m] = (f32x4){biasv, biasv, biasv, biasv};
      if (t > 0) {
        const unsigned short* Hrd = h2all + (size_t)(t - 1) * 65536;
#pragma unroll
        for (int kk = 0; kk < 32; ++kk) {
#pragma unroll
          for (int m = 0; m < 4; ++m) {
            bf16x8 a = *(const bf16x8*)(Hrd + (m * 16 + c) * 1024 + kk * 32 + q * 8);
            acc[m] = MFMA16x32(a, Breg[kk], acc[m]);
          }
        }
      }

      wait_slots(g1slots, (unsigned)(t + 1), poison);        // H1(t) available (G1 runs ahead)
      {
        const unsigned short* Hrd = h1ring + (t & 3) * 65536;
#pragma unroll
        for (int kk = 32; kk < 64; ++kk) {
#pragma unroll
          for (int m = 0; m < 4; ++m) {
            bf16x8 a = *(const bf16x8*)(Hrd + (m * 16 + c) * 1024 + (kk - 32) * 32 + q * 8);
            acc[m] = MFMA16x32(a, Breg[kk], acc[m]);
          }
        }
      }

#pragma unroll
      for (int m = 0; m < 4; ++m) {
#pragma unroll
        for (int r = 0; r < 4; ++r) {
          float v = acc[m][r];
          const int sb = (lane & 48) | (lane & 3);
          float vf = __shfl(v, sb, 64);
          float vi = __shfl(v, sb | 4, 64);
          float vo = __shfl(v, sb | 8, 64);
          float vc = __shfl(v, sb | 12, 64);
          float fg = 1.f / (1.f + __expf(-vf));
          float ig = 1.f / (1.f + __expf(-vi));
          float og = 1.f / (1.f + __expf(-vo));
          float e2 = __expf(2.f * vc);
          float ct = (e2 - 1.f) / (e2 + 1.f);
          float Cn = fg * Cst[m * 4 + r] + ig * ct;
          Cst[m * 4 + r] = Cn;
          float e2c = __expf(2.f * Cn);
          float Hn = og * (e2c - 1.f) / (e2c + 1.f);
          if ((lane & 12) == 0) {
            int row = m * 16 + q * 4 + r;
            h2all[((size_t)t * 64 + row) * 1024 + h_ew] = f2bf(Hn);
            if (t == 255) {
              outF[131072 + row * 1024 + h_ew] = Hn;  // H2 final
              outF[196608 + row * 1024 + h_ew] = Cn;  // C2 final
            }
          }
        }
      }
      publish_slot(g3slots, myslot, (unsigned)(t + 1));      // H2(t) published
    }
  }
}

// ---------------- output projection: Y = H2all @ Wout + bout ----------------
__global__ __launch_bounds__(256, 2) void k_gemm_out(
    const unsigned short* __restrict__ A, const unsigned short* __restrict__ Bt,
    const float* __restrict__ bout, float* __restrict__ C)
{
  __shared__ unsigned short As[128 * 32];
  __shared__ unsigned short Bs[128 * 32];
  const int tid = threadIdx.x, lane = tid & 63, wv = tid >> 6;
  const int c = lane & 15, q = lane >> 4;
  const int bn = blockIdx.x & 31, bm = blockIdx.x >> 5;
  const int wm = wv >> 1, wn = wv & 1;

  f32x4 acc[4][4];
#pragma unroll
  for (int m = 0; m < 4; ++m)
#pragma unroll
    for (int n = 0; n < 4; ++n) acc[m][n] = (f32x4){0.f, 0.f, 0.f, 0.f};

  const unsigned short* Abase = A + (size_t)(bm * 128) * 1024;
  const unsigned short* Bbase = Bt + (size_t)(bn * 128) * 1024;

  for (int kt = 0; kt < 32; ++kt) {
    if (kt) __syncthreads();
#pragma unroll
    for (int ch = 0; ch < 2; ++ch) {
      int o = ch * 4096 + tid * 16;          // byte offset within 8KB tile
      int row = o >> 6;
      int ks = (o & 63) >> 1;
      *(bf16x8*)&As[o >> 1] = *(const bf16x8*)(Abase + (size_t)row * 1024 + kt * 32 + ks);
      *(bf16x8*)&Bs[o >> 1] = *(const bf16x8*)(Bbase + (size_t)row * 1024 + kt * 32 + ks);
    }
    __syncthreads();
    bf16x8 af[4], bfr[4];
#pragma unroll
    for (int m = 0; m < 4; ++m) af[m] = *(const bf16x8*)&As[(wm * 64 + m * 16 + c) * 32 + q * 8];
#pragma unroll
    for (int n = 0; n < 4; ++n) bfr[n] = *(const bf16x8*)&Bs[(wn * 64 + n * 16 + c) * 32 + q * 8];
#pragma unroll
    for (int m = 0; m < 4; ++m)
#pragma unroll
      for (int n = 0; n < 4; ++n) acc[m][n] = MFMA16x32(af[m], bfr[n], acc[m][n]);
  }

#pragma unroll
  for (int n = 0; n < 4; ++n) {
    int col = bn * 128 + wn * 64 + n * 16 + c;
    float bo = bout[col];
#pragma unroll
    for (int m = 0; m < 4; ++m) {
      int row0 = bm * 128 + wm * 64 + m * 16 + q * 4;
#pragma unroll
      for (int r = 0; r < 4; ++r)
        C[(size_t)(row0 + r) * 4096 + col] = acc[m][n][r] + bo;
    }
  }
}

extern "C" void kernel_launch(void* const* d_in, const int* in_sizes, int n_in,
                              void* d_out, int out_size, void* d_ws, size_t ws_size,
                              hipStream_t stream) {
  const int* tokens = (const int*)d_in[0];
  const float* W1 = (const float*)d_in[1];
  const float* b1 = (const float*)d_in[2];
  const float* W2 = (const float*)d_in[3];
  const float* b2 = (const float*)d_in[4];
  const float* Wout = (const float*)d_in[5];
  const float* bout = (const float*)d_in[6];

  char* ws = (char*)d_ws;
  unsigned short* g1blob = (unsigned short*)(ws + WS_G1BLOB);
  unsigned short* g3blob = (unsigned short*)(ws + WS_G3BLOB);
  unsigned short* woutT  = (unsigned short*)(ws + WS_WOUTT);
  unsigned short* h1ring = (unsigned short*)(ws + WS_H1RING);
  unsigned*       syncb  = (unsigned*)(ws + WS_SYNC);
  unsigned short* h2all  = (unsigned short*)(ws + WS_H2ALL);

  float* outY = (float*)d_out;
  float* outF = outY + 67108864;   // Y then H1,C1,H2,C2

  hipLaunchKernelGGL(k_init, dim3(16), dim3(256), 0, stream, syncb, 4096);
  hipLaunchKernelGGL(k_pack_g1, dim3(2048), dim3(256), 0, stream, W1, g1blob);
  hipLaunchKernelGGL(k_pack_g3, dim3(4096), dim3(256), 0, stream, W2, g3blob);
  hipLaunchKernelGGL(k_pack_woutT, dim3(16384), dim3(256), 0, stream, Wout, woutT);

  hipLaunchKernelGGL(k_lstm, dim3(128), dim3(256), 0, stream,
                     tokens, W1, b1, b2, g1blob, g3blob, h1ring, h2all, outF, syncb);

  hipLaunchKernelGGL(k_gemm_out, dim3(4096), dim3(256), 0, stream, h2all, woutT, bout, outY);
}